// Round 1
// baseline (557.772 us; speedup 1.0000x reference)
//
#include <hip/hip_runtime.h>
#include <hip/hip_bf16.h>
#include <math.h>

#define NB 64          // batch
#define NS 4096        // seq
#define NC 21          // classes
#define NCC 441        // NC*NC
#define TSTEPS 200

// ws layout (floats): [0, NB) = alpha per batch ; [NB + b*NCC, ...) = logq[b] (441 floats)

__global__ __launch_bounds__(512) void schedule_kernel(const int* __restrict__ t,
                                                       float* __restrict__ ws) {
    int b = blockIdx.x;
    __shared__ float s_alpha;
    if (threadIdx.x == 0) {
        int tb = t[b];
        const float HPI = 1.5707963267948966f;
        const float P = 1e-4f;
        float cum = 1.0f;
        float alpha = 1.0f;
        for (int i = 0; i < TSTEPS; ++i) {
            float s0 = ((float)i / (float)TSTEPS + P) / (1.0f + P) * HPI;
            float s1 = ((float)(i + 1) / (float)TSTEPS + P) / (1.0f + P) * HPI;
            float c0 = cosf(s0);
            float c1 = cosf(s1);
            float beta = 1.0f - (c1 * c1) / (c0 * c0);
            beta = fminf(fmaxf(beta, 0.0f), 0.999f);
            cum *= (1.0f - beta);
            if (i == tb) { alpha = cum; break; }
        }
        s_alpha = alpha;
        ws[b] = alpha;
    }
    __syncthreads();
    float a = s_alpha;
    float off = (1.0f - a) / (float)NC;
    float* lq = ws + NB + (size_t)b * NCC;
    for (int k = threadIdx.x; k < NCC; k += blockDim.x) {
        // diagonal of the 21x21 tile lives at k % 22 == 0
        float q = off + ((k % 22) == 0 ? a : 0.0f);
        lq[k] = logf(q + 1e-10f);
    }
}

__global__ __launch_bounds__(256) void logits_kernel(const float* __restrict__ x0,
                                                     const float* __restrict__ ws,
                                                     float* __restrict__ out) {
    __shared__ float s_logq[NCC];
    __shared__ float s_x[256 * NC];   // 21.5 KB: x tile, reused for results
    const int blocksPerBatch = NS / 256;   // 16
    int b  = blockIdx.x / blocksPerBatch;
    int p0 = (blockIdx.x % blocksPerBatch) * 256;

    const float* lq = ws + NB + (size_t)b * NCC;
    for (int k = threadIdx.x; k < NCC; k += 256) s_logq[k] = lq[k];

    size_t base = ((size_t)b * NS + p0) * NC;
    for (int i = threadIdx.x; i < 256 * NC; i += 256) s_x[i] = x0[base + i];
    __syncthreads();

    float x[NC];
#pragma unroll
    for (int c = 0; c < NC; ++c) x[c] = s_x[threadIdx.x * NC + c];

    float acc[NC];
#pragma unroll
    for (int d = 0; d < NC; ++d) acc[d] = 0.0f;
#pragma unroll
    for (int c = 0; c < NC; ++c) {
        float xc = x[c];
#pragma unroll
        for (int d = 0; d < NC; ++d)
            acc[d] = fmaf(xc, s_logq[c * NC + d], acc[d]);
    }
    __syncthreads();
#pragma unroll
    for (int d = 0; d < NC; ++d) s_x[threadIdx.x * NC + d] = acc[d];
    __syncthreads();
    for (int i = threadIdx.x; i < 256 * NC; i += 256) out[base + i] = s_x[i];
}

__global__ __launch_bounds__(256) void qt_kernel(const float* __restrict__ ws,
                                                 float* __restrict__ qt) {
    int b = blockIdx.y;
    float a = ws[b];
    float off = (1.0f - a) / (float)NC;
    const unsigned N4 = NS * NCC / 4;   // 451584 float4 per batch
    float4* dst = (float4*)(qt + (size_t)b * NS * NCC);
    unsigned stride = gridDim.x * blockDim.x;
    for (unsigned i4 = blockIdx.x * blockDim.x + threadIdx.x; i4 < N4; i4 += stride) {
        unsigned f  = i4 * 4u;
        unsigned k0 = f % 441u;     // position within the repeating 441 tile
        unsigned r0 = k0 % 22u;
        float4 v;
        float* vp = (float*)&v;
#pragma unroll
        for (int m = 0; m < 4; ++m) {
            unsigned km = k0 + (unsigned)m;
            unsigned rm = r0 + (unsigned)m;
            if (km >= 441u) rm = km - 441u;   // wrapped: 0,1,2 ; diag iff 0
            bool diag = (rm == 0u) || (rm == 22u);
            vp[m] = off + (diag ? a : 0.0f);
        }
        dst[i4] = v;
    }
}

extern "C" void kernel_launch(void* const* d_in, const int* in_sizes, int n_in,
                              void* d_out, int out_size, void* d_ws, size_t ws_size,
                              hipStream_t stream) {
    const float* x0 = (const float*)d_in[0];
    const int*   t  = (const int*)d_in[1];
    float* out    = (float*)d_out;
    float* logits = out;                                // [B,S,C]
    float* qt     = out + (size_t)NB * NS * NC;         // [B,S,C,C]
    float* ws     = (float*)d_ws;

    schedule_kernel<<<NB, 512, 0, stream>>>(t, ws);
    logits_kernel<<<(NB * NS) / 256, 256, 0, stream>>>(x0, ws, logits);
    qt_kernel<<<dim3(128, NB), 256, 0, stream>>>(ws, qt);
}

// Round 3
// 522.449 us; speedup vs baseline: 1.0676x; 1.0676x over previous
//
#include <hip/hip_runtime.h>
#include <hip/hip_bf16.h>
#include <math.h>

#define NB 64          // batch
#define NS 4096        // seq
#define NC 21          // classes
#define NCC 441        // NC*NC
#define TSTEPS 200

// ws layout: float4 per batch: {qo, qd, Loff, Ldelta}
//   qo = (1-a)/21, qd = qo + a, Loff = log(qo+eps), Ldelta = log(qd+eps)-Loff

__global__ __launch_bounds__(64) void schedule_kernel(const int* __restrict__ t,
                                                      float4* __restrict__ ws) {
    int b = threadIdx.x;            // one batch per lane, single block of 64
    int tb = t[b];
    const float HPI = 1.5707963267948966f;
    const float P = 1e-4f;
    float cum = 1.0f;
    float alpha = 1.0f;
    float c0 = __cosf(P / (1.0f + P) * HPI);           // cos at step 0
    for (int i = 0; i < TSTEPS; ++i) {
        float s1 = ((float)(i + 1) / (float)TSTEPS + P) / (1.0f + P) * HPI;
        float c1 = __cosf(s1);
        float beta = 1.0f - (c1 * c1) / (c0 * c0);
        beta = fminf(fmaxf(beta, 0.0f), 0.999f);
        cum *= (1.0f - beta);
        if (i == tb) alpha = cum;   // no break: keep wave uniform
        c0 = c1;
    }
    float qo = (1.0f - alpha) / (float)NC;
    float qd = qo + alpha;
    float Loff  = logf(qo + 1e-10f);
    float Ldiag = logf(qd + 1e-10f);
    ws[b] = make_float4(qo, qd, Loff, Ldiag - Loff);
}

// Fused: 17408 blocks. Every 17th block (id%17==0: 1024 blocks) computes
// logits (256 rows each); the other 16384 stream q_t (1764 float4 each:
// 16 repeats of the 441-float 21x21 tile, pattern-aligned per chunk).
__global__ __launch_bounds__(256) void fused_kernel(const float* __restrict__ x0,
                                                    const float4* __restrict__ ws,
                                                    float* __restrict__ logits,
                                                    float* __restrict__ qt) {
    __shared__ float4 s4[1344];     // 21.5 KB, shared by both paths
    const int tid = threadIdx.x;
    const int id = blockIdx.x;
    const int div17 = id / 17;

    if (id % 17 != 0) {
        // ---------------- q_t path ----------------
        const int blk = id - 1 - div17;          // 0..16383
        const int b = blk >> 8;                  // 256 chunks per batch
        const float4 w = ws[b];
        const float qo = w.x, qd = w.y;

        // Build the 441-float4 repeating tile (1764 floats = LCM(4,441)).
        // float j: pos = j % 441, diag iff pos % 22 == 0.
        for (int k = tid; k < NCC; k += 256) {
            int p0 = 4 * k;                       // < 1764
            if (p0 >= 882) p0 -= 882;
            if (p0 >= 441) p0 -= 441;
            float4 v;
            float* vp = (float*)&v;
#pragma unroll
            for (int m = 0; m < 4; ++m) {
                int pm = p0 + m;
                if (pm >= 441) pm -= 441;
                vp[m] = (pm % 22 == 0) ? qd : qo;
            }
            s4[k] = v;
        }
        __syncthreads();

        float4* dst = (float4*)qt + (size_t)blk * 1764;
        for (int i = tid; i < 1764; i += 256) {
            int m = i;
            if (m >= 882) m -= 882;
            if (m >= 441) m -= 441;
            dst[i] = s4[m];
        }
    } else {
        // ---------------- logits path ----------------
        const int blk = div17;                    // 0..1023, 256 rows each
        const int b = blk >> 4;                   // 16 blocks per batch
        const float4 w = ws[b];
        const float Loff = w.z, Ldelta = w.w;

        const float4* g = (const float4*)x0 + (size_t)blk * 1344;
#pragma unroll
        for (int k = 0; k < 6; ++k) {
            int idx = tid + k * 256;
            if (idx < 1344) s4[idx] = g[idx];
        }
        __syncthreads();

        float* sf = (float*)s4;
        float x[NC];
        float S = 0.0f;
#pragma unroll
        for (int c = 0; c < NC; ++c) { x[c] = sf[tid * NC + c]; S += x[c]; }
        float base = Loff * S;
#pragma unroll
        for (int d = 0; d < NC; ++d) sf[tid * NC + d] = fmaf(Ldelta, x[d], base);
        __syncthreads();

        float4* o = (float4*)logits + (size_t)blk * 1344;
#pragma unroll
        for (int k = 0; k < 6; ++k) {
            int idx = tid + k * 256;
            if (idx < 1344) o[idx] = s4[idx];
        }
    }
}

extern "C" void kernel_launch(void* const* d_in, const int* in_sizes, int n_in,
                              void* d_out, int out_size, void* d_ws, size_t ws_size,
                              hipStream_t stream) {
    const float* x0 = (const float*)d_in[0];
    const int*   t  = (const int*)d_in[1];
    float* out    = (float*)d_out;
    float* logits = out;                                // [B,S,C]
    float* qt     = out + (size_t)NB * NS * NC;         // [B,S,C,C]
    float4* ws    = (float4*)d_ws;

    schedule_kernel<<<1, 64, 0, stream>>>(t, ws);
    fused_kernel<<<17408, 256, 0, stream>>>(x0, ws, logits, qt);
}